// Round 8
// baseline (266.193 us; speedup 1.0000x reference)
//
#include <hip/hip_runtime.h>
#include <hip/hip_bf16.h>

typedef unsigned short u16;
typedef u16 u16x8 __attribute__((ext_vector_type(8)));
typedef u16 u16x4 __attribute__((ext_vector_type(4)));
typedef __bf16 bf16x8 __attribute__((ext_vector_type(8)));
typedef float f32x4 __attribute__((ext_vector_type(4)));

#define B_ 2
#define S_ 2048
#define E_ 1024
#define H_ 16
#define D_ 64
// 1/sqrt(64) * log2(e): folds attention scale + exp->exp2 into Q projection.
#define QSCALE 0.18033688011112042f

__device__ __forceinline__ u16 f2bf(float f) {
    return __builtin_bit_cast(u16, static_cast<__bf16>(f));  // RNE
}
__device__ __forceinline__ float bf2f(unsigned u) {
    return __builtin_bit_cast(float, u << 16);
}

// async global->LDS, 16B per lane; LDS dest = wave-uniform base + lane*16
__device__ __forceinline__ void glds16(const u16* g, u16* l) {
    __builtin_amdgcn_global_load_lds(
        (const __attribute__((address_space(1))) unsigned int*)g,
        (__attribute__((address_space(3))) unsigned int*)l, 16, 0, 0);
}

#define VMCNT0 asm volatile("s_waitcnt vmcnt(0)" ::: "memory")
// raw barrier: does NOT drain vmcnt (unlike __syncthreads) -> counted waits work
#define RAW_BAR() do { __builtin_amdgcn_s_barrier(); asm volatile("" ::: "memory"); } while (0)

// LDS tiles: [rows][64 bf16] = 128B rows, XOR-swizzle byte ^= (row&7)<<4.
// Staging uses pre-swizzled GLOBAL source (seg ^= row&7) + linear LDS dest,
// reads apply the same involution (both-sides rule).
__device__ __forceinline__ bf16x8 lds_read8(const u16* base, int row, int k) {
    const char* p = (const char*)base + (((row * 128) + (k * 2)) ^ ((row & 7) << 4));
    return __builtin_bit_cast(bf16x8, *(const u16x8*)p);
}

__device__ __forceinline__ f32x4 mfma16x16(bf16x8 a, bf16x8 b, f32x4 c) {
    return __builtin_amdgcn_mfma_f32_16x16x32_bf16(a, b, c, 0, 0, 0);
}

// ---------------------------------------------------------------------------
// fp32 -> bf16 pre-convert: q,k,v (3 x 4M elems) + Wq,Wk,Wv,Wo (4 x 1M elems)
// ---------------------------------------------------------------------------
__global__ __launch_bounds__(256) void cvt_kernel(const float* __restrict__ q,
                                                  const float* __restrict__ k,
                                                  const float* __restrict__ v,
                                                  const float* __restrict__ wq,
                                                  const float* __restrict__ wk,
                                                  const float* __restrict__ wv,
                                                  const float* __restrict__ wo,
                                                  u16* __restrict__ qkv_dst,
                                                  u16* __restrict__ w_dst) {
    const int bid = blockIdx.x;
    const float* src;
    u16* dst;
    if (bid < 6144) {
        const int t = bid >> 11, lb = bid & 2047;
        src = (t == 0 ? q : t == 1 ? k : v) + (size_t)lb * 2048;
        dst = qkv_dst + (size_t)t * 4194304 + (size_t)lb * 2048;
    } else {
        const int t = (bid - 6144) >> 9, lb = (bid - 6144) & 511;
        src = (t == 0 ? wq : t == 1 ? wk : t == 2 ? wv : wo) + (size_t)lb * 2048;
        dst = w_dst + (size_t)t * 1048576 + (size_t)lb * 2048;
    }
    const int off = threadIdx.x * 8;
    f32x4 a = *(const f32x4*)(src + off);
    f32x4 b = *(const f32x4*)(src + off + 4);
    u16x8 o;
#pragma unroll
    for (int i = 0; i < 4; ++i) { o[i] = f2bf(a[i]); o[4 + i] = f2bf(b[i]); }
    *(u16x8*)(dst + off) = o;
}

// ---------------------------------------------------------------------------
// Fused Q/K/V projection GEMM, 128x128 tile. z = blockIdx.z selects {q,k,v}.
// ---------------------------------------------------------------------------
__global__ __launch_bounds__(256) void gemm_qkv(const u16* __restrict__ qkv_bf,
                                                const u16* __restrict__ w_bf,
                                                const float* __restrict__ bq,
                                                const float* __restrict__ bk,
                                                const float* __restrict__ bv,
                                                u16* __restrict__ outbase) {
    const int z = blockIdx.z;
    const u16* A = qkv_bf + (size_t)z * 4194304;
    const u16* W = w_bf + (size_t)z * 1048576;
    const float* bias = (z == 0) ? bq : (z == 1) ? bk : bv;
    u16* outp = outbase + (size_t)z * 4194304;

    const int n0 = blockIdx.x * 128;
    const int m0 = blockIdx.y * 128;
    const int tid = threadIdx.x;
    const int lane = tid & 63, g = lane >> 4, c = lane & 15;
    const int w = tid >> 6, wm = w >> 1, wn = w & 1;

    __shared__ u16 lA[2][8192];  // 128 x 64
    __shared__ u16 lB[2][8192];  // 128 x 64

    auto stage = [&](int buf, int kt) {
#pragma unroll
        for (int i = 0; i < 4; ++i) {
            const int chunk = (w * 4 + i) * 64 + lane;  // 0..1023
            const int r = chunk >> 3, sg = chunk & 7, ss = sg ^ (r & 7);
            glds16(A + (size_t)(m0 + r) * 1024 + kt * 64 + ss * 8, &lA[buf][(w * 4 + i) * 512]);
            glds16(W + (size_t)(n0 + r) * 1024 + kt * 64 + ss * 8, &lB[buf][(w * 4 + i) * 512]);
        }
    };

    f32x4 acc[4][4] = {};
    stage(0, 0);
    VMCNT0;
    __syncthreads();

    for (int kt = 0; kt < 16; ++kt) {
        const int buf = kt & 1;
        if (kt < 15) stage(buf ^ 1, kt + 1);
#pragma unroll
        for (int ks = 0; ks < 2; ++ks) {
            bf16x8 af[4], bfr[4];
#pragma unroll
            for (int fm = 0; fm < 4; ++fm) af[fm] = lds_read8(lA[buf], wm * 64 + fm * 16 + c, g * 8 + ks * 32);
#pragma unroll
            for (int fn = 0; fn < 4; ++fn) bfr[fn] = lds_read8(lB[buf], wn * 64 + fn * 16 + c, g * 8 + ks * 32);
#pragma unroll
            for (int fm = 0; fm < 4; ++fm)
#pragma unroll
                for (int fn = 0; fn < 4; ++fn)
                    acc[fm][fn] = mfma16x16(af[fm], bfr[fn], acc[fm][fn]);
        }
        VMCNT0;   // only the 8 prefetch loads are outstanding
        RAW_BAR();
    }

    float bv_[4];
#pragma unroll
    for (int fn = 0; fn < 4; ++fn) bv_[fn] = bias[n0 + wn * 64 + fn * 16 + c];

#pragma unroll
    for (int fm = 0; fm < 4; ++fm) {
#pragma unroll
        for (int fn = 0; fn < 4; ++fn) {
            const int mbase = m0 + wm * 64 + fm * 16 + g * 4;
            const int n = n0 + wn * 64 + fn * 16 + c;
            if (z == 2) {
                u16x4 vv;
#pragma unroll
                for (int r = 0; r < 4; ++r) vv[r] = f2bf(acc[fm][fn][r] + bv_[fn]);
                const int b = mbase >> 11, s = mbase & 2047, h = n >> 6, d = n & 63;
                u16* dst = outp + ((size_t)((b * 16 + h) * 64 + d)) * 2048 + s;
                *(u16x4*)dst = vv;
            } else {
                const float sc = (z == 0) ? QSCALE : 1.0f;
#pragma unroll
                for (int r = 0; r < 4; ++r) {
                    const float val = (acc[fm][fn][r] + bv_[fn]) * sc;
                    const int m = mbase + r;
                    const int b = m >> 11, s = m & 2047, h = n >> 6, d = n & 63;
                    outp[((size_t)((b * 16 + h) * 2048 + s)) * 64 + d] = f2bf(val);
                }
            }
        }
    }
}

// ---------------------------------------------------------------------------
// Output GEMM, 128x128 tile: fp32 out[m][n] = sum_k A[m][k]*W[n][k] + bias[n]
// ---------------------------------------------------------------------------
__global__ __launch_bounds__(256) void gemm_out(const u16* __restrict__ A,
                                                const u16* __restrict__ W,
                                                const float* __restrict__ bias,
                                                float* __restrict__ outp) {
    const int n0 = blockIdx.x * 128;
    const int m0 = blockIdx.y * 128;
    const int tid = threadIdx.x;
    const int lane = tid & 63, g = lane >> 4, c = lane & 15;
    const int w = tid >> 6, wm = w >> 1, wn = w & 1;

    __shared__ u16 lA[2][8192];
    __shared__ u16 lB[2][8192];

    auto stage = [&](int buf, int kt) {
#pragma unroll
        for (int i = 0; i < 4; ++i) {
            const int chunk = (w * 4 + i) * 64 + lane;
            const int r = chunk >> 3, sg = chunk & 7, ss = sg ^ (r & 7);
            glds16(A + (size_t)(m0 + r) * 1024 + kt * 64 + ss * 8, &lA[buf][(w * 4 + i) * 512]);
            glds16(W + (size_t)(n0 + r) * 1024 + kt * 64 + ss * 8, &lB[buf][(w * 4 + i) * 512]);
        }
    };

    f32x4 acc[4][4] = {};
    stage(0, 0);
    VMCNT0;
    __syncthreads();

    for (int kt = 0; kt < 16; ++kt) {
        const int buf = kt & 1;
        if (kt < 15) stage(buf ^ 1, kt + 1);
#pragma unroll
        for (int ks = 0; ks < 2; ++ks) {
            bf16x8 af[4], bfr[4];
#pragma unroll
            for (int fm = 0; fm < 4; ++fm) af[fm] = lds_read8(lA[buf], wm * 64 + fm * 16 + c, g * 8 + ks * 32);
#pragma unroll
            for (int fn = 0; fn < 4; ++fn) bfr[fn] = lds_read8(lB[buf], wn * 64 + fn * 16 + c, g * 8 + ks * 32);
#pragma unroll
            for (int fm = 0; fm < 4; ++fm)
#pragma unroll
                for (int fn = 0; fn < 4; ++fn)
                    acc[fm][fn] = mfma16x16(af[fm], bfr[fn], acc[fm][fn]);
        }
        VMCNT0;
        RAW_BAR();
    }

    float bv_[4];
#pragma unroll
    for (int fn = 0; fn < 4; ++fn) bv_[fn] = bias[n0 + wn * 64 + fn * 16 + c];

#pragma unroll
    for (int fm = 0; fm < 4; ++fm)
#pragma unroll
        for (int fn = 0; fn < 4; ++fn) {
            const int mbase = m0 + wm * 64 + fm * 16 + g * 4;
            const int n = n0 + wn * 64 + fn * 16 + c;
#pragma unroll
            for (int r = 0; r < 4; ++r)
                outp[(size_t)(mbase + r) * 1024 + n] = acc[fm][fn][r] + bv_[fn];
        }
}

// ---------------------------------------------------------------------------
// Pass A standalone, occupancy-oriented: computes linv[b,h,s] = 1/sum 2^s.
// QBLK=64, grid 1024, 4 waves x 16 q-rows, Q in REGISTERS, LDS = K dbuf
// 32 KB only -> 4 blocks/CU resident = 16 waves/CU (2x the fused version).
// The exp-heavy VALU chain + staging barriers hide under TLP.
// ---------------------------------------------------------------------------
__global__ __launch_bounds__(256) void attn_sums(const u16* __restrict__ Qh,
                                                 const u16* __restrict__ Kh,
                                                 float* __restrict__ linv_ws) {
    const int bid = blockIdx.x;
    const int sw = ((bid & 7) << 7) + (bid >> 3);  // bijective: 1024 % 8 == 0
    const int bh = sw >> 5, qt = sw & 31;          // head, q-tile of 64
    const int tid = threadIdx.x;
    const int lane = tid & 63, g = lane >> 4, c = lane & 15;
    const int w = tid >> 6;

    __shared__ u16 lK[2][8192];  // 128 x 64 double-buffered

    const u16* Qbase = Qh + ((size_t)bh * S_ + qt * 64) * D_;
    const u16* Kbase = Kh + (size_t)bh * S_ * D_;

    // Q hoist: wave w owns q rows [w*16, w*16+16) (verified layout, R5)
    bf16x8 qreg[2];
#pragma unroll
    for (int ks = 0; ks < 2; ++ks)
        qreg[ks] = __builtin_bit_cast(bf16x8,
            *(const u16x8*)(Qbase + (size_t)(w * 16 + c) * 64 + ks * 32 + g * 8));

    auto stageK128 = [&](int buf, int kt2) {
#pragma unroll
        for (int i = 0; i < 4; ++i) {
            const int chunk = (w * 4 + i) * 64 + lane;
            const int r = chunk >> 3, sg = chunk & 7, ss = sg ^ (r & 7);
            glds16(Kbase + (size_t)(kt2 * 128 + r) * 64 + ss * 8, &lK[buf][(w * 4 + i) * 512]);
        }
    };

    stageK128(0, 0);
    VMCNT0;
    __syncthreads();

    float l_run = 0.f;  // row-sum for q-row (w*16 + c)

    for (int kt2 = 0; kt2 < 16; ++kt2) {
        const int buf = kt2 & 1;
        if (kt2 < 15) stageK128(buf ^ 1, kt2 + 1);

#pragma unroll
        for (int sub = 0; sub < 2; ++sub) {
            f32x4 s[4] = {};
            __builtin_amdgcn_s_setprio(1);
#pragma unroll
            for (int ks = 0; ks < 2; ++ks) {
                bf16x8 a[4];
#pragma unroll
                for (int kf = 0; kf < 4; ++kf)
                    a[kf] = lds_read8(lK[buf], sub * 64 + kf * 16 + c, g * 8 + ks * 32);
#pragma unroll
                for (int kf = 0; kf < 4; ++kf)
                    s[kf] = mfma16x16(a[kf], qreg[ks], s[kf]);
            }
            __builtin_amdgcn_s_setprio(0);
            float ts = 0.f;
#pragma unroll
            for (int kf = 0; kf < 4; ++kf)
#pragma unroll
                for (int r = 0; r < 4; ++r) ts += exp2f(s[kf][r]);
            ts += __shfl_xor(ts, 16);
            ts += __shfl_xor(ts, 32);
            l_run += ts;
        }
        VMCNT0;
        RAW_BAR();
    }

    if (lane < 16)
        linv_ws[(size_t)bh * S_ + qt * 64 + w * 16 + c] = 1.f / l_run;
}

// ---------------------------------------------------------------------------
// Pass B standalone (R7 pass-B verbatim; linv read from ws):
// block = (bh, 128 q-rows), XCD-swizzled, 4 waves x 32 q-rows, lQ staged.
// KVBLK=64 dbuf; P -> bf16 per-wave LDS; NT attnW stores (from myP) issued
// BEFORE the PV cluster; counted vmcnt(8) + raw barrier.
// LDS: lQ 16K + lKV 32K + lP 16K = 64 KB -> 2 blocks/CU (unchanged).
// ---------------------------------------------------------------------------
__global__ __launch_bounds__(256) void attn_pv(const u16* __restrict__ Qh,
                                               const u16* __restrict__ Kh,
                                               const u16* __restrict__ Vt,
                                               const float* __restrict__ linv_ws,
                                               float* __restrict__ attnW,
                                               u16* __restrict__ Obf) {
    const int bid = blockIdx.x;
    const int sw = ((bid & 7) << 6) + (bid >> 3);  // bijective: 512 % 8 == 0
    const int bh = sw >> 4, qt = sw & 15;
    const int tid = threadIdx.x;
    const int lane = tid & 63, g = lane >> 4, c = lane & 15;
    const int w = tid >> 6;

    __shared__ u16 lQ[8192];        // 128 x 64
    __shared__ u16 lKV[2][8192];    // K64 | V64 double-buffered
    __shared__ u16 lP[4][2048];     // per-wave 32 x 64

    const u16* Qbase = Qh + ((size_t)bh * S_ + qt * 128) * D_;
    const u16* Kbase = Kh + (size_t)bh * S_ * D_;
    const u16* Vbase = Vt + (size_t)bh * D_ * S_;

#pragma unroll
    for (int i = 0; i < 4; ++i) {
        const int chunk = (w * 4 + i) * 64 + lane;
        const int r = chunk >> 3, sg = chunk & 7, ss = sg ^ (r & 7);
        glds16(Qbase + r * 64 + ss * 8, &lQ[(w * 4 + i) * 512]);
    }
    auto stageKV64 = [&](int buf, int kt) {
#pragma unroll
        for (int i = 0; i < 2; ++i) {
            const int chunk = (w * 2 + i) * 64 + lane;
            const int r = chunk >> 3, sg = chunk & 7, ss = sg ^ (r & 7);
            glds16(Kbase + (size_t)(kt * 64 + r) * 64 + ss * 8, &lKV[buf][(w * 2 + i) * 512]);
            glds16(Vbase + (size_t)r * S_ + kt * 64 + ss * 8, &lKV[buf][4096 + (w * 2 + i) * 512]);
        }
    };

    const float linv[2] = {
        linv_ws[(size_t)bh * S_ + qt * 128 + w * 32 + c],
        linv_ws[(size_t)bh * S_ + qt * 128 + w * 32 + 16 + c]};

    f32x4 o[2][4] = {};
    stageKV64(0, 0);
    VMCNT0;
    __syncthreads();

    for (int kt = 0; kt < 32; ++kt) {
        const int buf = kt & 1;
        if (kt < 31) stageKV64(buf ^ 1, kt + 1);

        f32x4 s[4][2] = {};
        __builtin_amdgcn_s_setprio(1);
#pragma unroll
        for (int ks = 0; ks < 2; ++ks) {
            bf16x8 a[4], b[2];
#pragma unroll
            for (int kf = 0; kf < 4; ++kf)
                a[kf] = lds_read8(lKV[buf], kf * 16 + c, g * 8 + ks * 32);
#pragma unroll
            for (int qf = 0; qf < 2; ++qf)
                b[qf] = lds_read8(lQ, w * 32 + qf * 16 + c, g * 8 + ks * 32);
#pragma unroll
            for (int kf = 0; kf < 4; ++kf)
#pragma unroll
                for (int qf = 0; qf < 2; ++qf)
                    s[kf][qf] = mfma16x16(a[kf], b[qf], s[kf][qf]);
        }
        __builtin_amdgcn_s_setprio(0);

        u16* myP = lP[w];
#pragma unroll
        for (int qf = 0; qf < 2; ++qf) {
#pragma unroll
            for (int kf = 0; kf < 4; ++kf) {
                f32x4 p4;
#pragma unroll
                for (int r = 0; r < 4; ++r) p4[r] = exp2f(s[kf][qf][r]) * linv[qf];
#pragma unroll
                for (int rp = 0; rp < 2; ++rp) {
                    const unsigned pk = (unsigned)f2bf(p4[2 * rp]) |
                                        ((unsigned)f2bf(p4[2 * rp + 1]) << 16);
                    const int row = qf * 16 + c;
                    const int col = kf * 16 + g * 4 + 2 * rp;
                    *(unsigned*)((char*)myP + (((row * 128) + (col * 2)) ^ ((row & 7) << 4))) = pk;
                }
            }
        }

        // Coalesced NT attnW store from myP, issued BEFORE PV.
        {
            const size_t qbase = (size_t)bh * S_ + (size_t)(qt * 128 + w * 32);
#pragma unroll
            for (int j = 0; j < 8; ++j) {
                const int row = j * 4 + g;
                const unsigned long long pv8 = *(const unsigned long long*)(
                    (const char*)myP + (((row * 128) + c * 8) ^ ((row & 7) << 4)));
                f32x4 o4;
                o4[0] = bf2f((unsigned)(pv8 & 0xffffu));
                o4[1] = bf2f((unsigned)((pv8 >> 16) & 0xffffu));
                o4[2] = bf2f((unsigned)((pv8 >> 32) & 0xffffu));
                o4[3] = bf2f((unsigned)((pv8 >> 48) & 0xffffu));
                __builtin_nontemporal_store(
                    o4, (f32x4*)(attnW + (qbase + row) * S_ + kt * 64 + c * 4));
            }
        }

        // PV: o[q][d] += P[q][kv] * V[kv][d]
        __builtin_amdgcn_s_setprio(1);
#pragma unroll
        for (int ks = 0; ks < 2; ++ks) {
            bf16x8 pa[2], vb[4];
#pragma unroll
            for (int fm = 0; fm < 2; ++fm) pa[fm] = lds_read8(myP, fm * 16 + c, g * 8 + ks * 32);
#pragma unroll
            for (int fn = 0; fn < 4; ++fn) vb[fn] = lds_read8(lKV[buf] + 4096, fn * 16 + c, g * 8 + ks * 32);
#pragma unroll
            for (int fm = 0; fm < 2; ++fm)
#pragma unroll
                for (int fn = 0; fn < 4; ++fn)
                    o[fm][fn] = mfma16x16(pa[fm], vb[fn], o[fm][fn]);
        }
        __builtin_amdgcn_s_setprio(0);

        // counted wait: this tile's 8 stores stay in flight; the oldest
        // outstanding (this tile's 4 prefetch loads) must land.
        asm volatile("s_waitcnt vmcnt(8)" ::: "memory");
        RAW_BAR();
    }

    // write O as bf16 head-merged [b][s][h*64+d] (A-operand of final GEMM)
    const int b2 = bh >> 4, h = bh & 15;
#pragma unroll
    for (int fm = 0; fm < 2; ++fm)
#pragma unroll
        for (int fn = 0; fn < 4; ++fn)
#pragma unroll
            for (int r = 0; r < 4; ++r) {
                const int q = qt * 128 + w * 32 + fm * 16 + g * 4 + r;
                const int d = fn * 16 + c;
                __builtin_nontemporal_store(
                    f2bf(o[fm][fn][r]),
                    &Obf[((size_t)(b2 * S_ + q)) * E_ + h * 64 + d]);
            }
}

extern "C" void kernel_launch(void* const* d_in, const int* in_sizes, int n_in,
                              void* d_out, int out_size, void* d_ws, size_t ws_size,
                              hipStream_t stream) {
    const float* query = (const float*)d_in[0];
    const float* key_ = (const float*)d_in[1];
    const float* value = (const float*)d_in[2];
    const float* Wq = (const float*)d_in[3];
    const float* bq = (const float*)d_in[4];
    const float* Wk = (const float*)d_in[5];
    const float* bk = (const float*)d_in[6];
    const float* Wv = (const float*)d_in[7];
    const float* bv = (const float*)d_in[8];
    const float* Wo = (const float*)d_in[9];
    const float* bo = (const float*)d_in[10];

    // ws layout (u16 units):
    // [0,12M)   qbf,kbf,vbf   (Obf aliases [0,4M); linv uses [8M,8M+128K),
    //           both dead after gemm_qkv consumes them)
    // [12M,16M) Wq,Wk,Wv,Wo bf16
    // [16M,28M) Qh, Kh, Vt
    u16* qkv_bf = (u16*)d_ws;
    u16* w_bf = qkv_bf + (size_t)12 * 1024 * 1024;
    u16* Qh = qkv_bf + (size_t)16 * 1024 * 1024;
    u16* Obf = qkv_bf;  // alias: q bf16 dead once projections finish
    float* linv_ws = (float*)(qkv_bf + (size_t)8 * 1024 * 1024);  // v-bf region

    float* out0 = (float*)d_out;                 // [B,S,E]
    float* attnW = out0 + (size_t)B_ * S_ * E_;  // [B,H,S,S]

    cvt_kernel<<<8192, 256, 0, stream>>>(query, key_, value, Wq, Wk, Wv, Wo, qkv_bf, w_bf);

    gemm_qkv<<<dim3(8, 32, 3), 256, 0, stream>>>(qkv_bf, w_bf, bq, bk, bv, Qh);

    attn_sums<<<1024, 256, 0, stream>>>(Qh, Qh + (size_t)4 * 1024 * 1024, linv_ws);

    attn_pv<<<512, 256, 0, stream>>>(Qh, Qh + (size_t)4 * 1024 * 1024,
                                     Qh + (size_t)8 * 1024 * 1024, linv_ws, attnW, Obf);

    gemm_out<<<dim3(8, 32), 256, 0, stream>>>(Obf, w_bf + (size_t)3 * 1024 * 1024, bo, (float*)d_out);
}

// Round 9
// 234.634 us; speedup vs baseline: 1.1345x; 1.1345x over previous
//
#include <hip/hip_runtime.h>
#include <hip/hip_bf16.h>

typedef unsigned short u16;
typedef u16 u16x8 __attribute__((ext_vector_type(8)));
typedef u16 u16x4 __attribute__((ext_vector_type(4)));
typedef __bf16 bf16x8 __attribute__((ext_vector_type(8)));
typedef float f32x4 __attribute__((ext_vector_type(4)));

#define B_ 2
#define S_ 2048
#define E_ 1024
#define H_ 16
#define D_ 64
// 1/sqrt(64) * log2(e): folds attention scale + exp->exp2 into Q projection.
#define QSCALE 0.18033688011112042f

__device__ __forceinline__ u16 f2bf(float f) {
    return __builtin_bit_cast(u16, static_cast<__bf16>(f));  // RNE
}
__device__ __forceinline__ float bf2f(unsigned u) {
    return __builtin_bit_cast(float, u << 16);
}

// async global->LDS, 16B per lane; LDS dest = wave-uniform base + lane*16
__device__ __forceinline__ void glds16(const u16* g, u16* l) {
    __builtin_amdgcn_global_load_lds(
        (const __attribute__((address_space(1))) unsigned int*)g,
        (__attribute__((address_space(3))) unsigned int*)l, 16, 0, 0);
}

#define VMCNT0 asm volatile("s_waitcnt vmcnt(0)" ::: "memory")
// raw barrier: does NOT drain vmcnt (unlike __syncthreads) -> counted waits work
#define RAW_BAR() do { __builtin_amdgcn_s_barrier(); asm volatile("" ::: "memory"); } while (0)

// LDS tiles: [rows][64 bf16] = 128B rows, XOR-swizzle byte ^= (row&7)<<4.
// Staging uses pre-swizzled GLOBAL source (seg ^= row&7) + linear LDS dest,
// reads apply the same involution (both-sides rule).
__device__ __forceinline__ bf16x8 lds_read8(const u16* base, int row, int k) {
    const char* p = (const char*)base + (((row * 128) + (k * 2)) ^ ((row & 7) << 4));
    return __builtin_bit_cast(bf16x8, *(const u16x8*)p);
}

__device__ __forceinline__ f32x4 mfma16x16(bf16x8 a, bf16x8 b, f32x4 c) {
    return __builtin_amdgcn_mfma_f32_16x16x32_bf16(a, b, c, 0, 0, 0);
}

// ---------------------------------------------------------------------------
// fp32 -> bf16 pre-convert: q,k,v (3 x 4M elems) + Wq,Wk,Wv,Wo (4 x 1M elems)
// ---------------------------------------------------------------------------
__global__ __launch_bounds__(256) void cvt_kernel(const float* __restrict__ q,
                                                  const float* __restrict__ k,
                                                  const float* __restrict__ v,
                                                  const float* __restrict__ wq,
                                                  const float* __restrict__ wk,
                                                  const float* __restrict__ wv,
                                                  const float* __restrict__ wo,
                                                  u16* __restrict__ qkv_dst,
                                                  u16* __restrict__ w_dst) {
    const int bid = blockIdx.x;
    const float* src;
    u16* dst;
    if (bid < 6144) {
        const int t = bid >> 11, lb = bid & 2047;
        src = (t == 0 ? q : t == 1 ? k : v) + (size_t)lb * 2048;
        dst = qkv_dst + (size_t)t * 4194304 + (size_t)lb * 2048;
    } else {
        const int t = (bid - 6144) >> 9, lb = (bid - 6144) & 511;
        src = (t == 0 ? wq : t == 1 ? wk : t == 2 ? wv : wo) + (size_t)lb * 2048;
        dst = w_dst + (size_t)t * 1048576 + (size_t)lb * 2048;
    }
    const int off = threadIdx.x * 8;
    f32x4 a = *(const f32x4*)(src + off);
    f32x4 b = *(const f32x4*)(src + off + 4);
    u16x8 o;
#pragma unroll
    for (int i = 0; i < 4; ++i) { o[i] = f2bf(a[i]); o[4 + i] = f2bf(b[i]); }
    *(u16x8*)(dst + off) = o;
}

// ---------------------------------------------------------------------------
// Fused Q/K/V projection GEMM, 128x128 tile. z = blockIdx.z selects {q,k,v}.
// ---------------------------------------------------------------------------
__global__ __launch_bounds__(256) void gemm_qkv(const u16* __restrict__ qkv_bf,
                                                const u16* __restrict__ w_bf,
                                                const float* __restrict__ bq,
                                                const float* __restrict__ bk,
                                                const float* __restrict__ bv,
                                                u16* __restrict__ outbase) {
    const int z = blockIdx.z;
    const u16* A = qkv_bf + (size_t)z * 4194304;
    const u16* W = w_bf + (size_t)z * 1048576;
    const float* bias = (z == 0) ? bq : (z == 1) ? bk : bv;
    u16* outp = outbase + (size_t)z * 4194304;

    const int n0 = blockIdx.x * 128;
    const int m0 = blockIdx.y * 128;
    const int tid = threadIdx.x;
    const int lane = tid & 63, g = lane >> 4, c = lane & 15;
    const int w = tid >> 6, wm = w >> 1, wn = w & 1;

    __shared__ u16 lA[2][8192];  // 128 x 64
    __shared__ u16 lB[2][8192];  // 128 x 64

    auto stage = [&](int buf, int kt) {
#pragma unroll
        for (int i = 0; i < 4; ++i) {
            const int chunk = (w * 4 + i) * 64 + lane;  // 0..1023
            const int r = chunk >> 3, sg = chunk & 7, ss = sg ^ (r & 7);
            glds16(A + (size_t)(m0 + r) * 1024 + kt * 64 + ss * 8, &lA[buf][(w * 4 + i) * 512]);
            glds16(W + (size_t)(n0 + r) * 1024 + kt * 64 + ss * 8, &lB[buf][(w * 4 + i) * 512]);
        }
    };

    f32x4 acc[4][4] = {};
    stage(0, 0);
    VMCNT0;
    __syncthreads();

    for (int kt = 0; kt < 16; ++kt) {
        const int buf = kt & 1;
        if (kt < 15) stage(buf ^ 1, kt + 1);
#pragma unroll
        for (int ks = 0; ks < 2; ++ks) {
            bf16x8 af[4], bfr[4];
#pragma unroll
            for (int fm = 0; fm < 4; ++fm) af[fm] = lds_read8(lA[buf], wm * 64 + fm * 16 + c, g * 8 + ks * 32);
#pragma unroll
            for (int fn = 0; fn < 4; ++fn) bfr[fn] = lds_read8(lB[buf], wn * 64 + fn * 16 + c, g * 8 + ks * 32);
#pragma unroll
            for (int fm = 0; fm < 4; ++fm)
#pragma unroll
                for (int fn = 0; fn < 4; ++fn)
                    acc[fm][fn] = mfma16x16(af[fm], bfr[fn], acc[fm][fn]);
        }
        VMCNT0;   // only the 8 prefetch loads are outstanding
        RAW_BAR();
    }

    float bv_[4];
#pragma unroll
    for (int fn = 0; fn < 4; ++fn) bv_[fn] = bias[n0 + wn * 64 + fn * 16 + c];

#pragma unroll
    for (int fm = 0; fm < 4; ++fm) {
#pragma unroll
        for (int fn = 0; fn < 4; ++fn) {
            const int mbase = m0 + wm * 64 + fm * 16 + g * 4;
            const int n = n0 + wn * 64 + fn * 16 + c;
            if (z == 2) {
                u16x4 vv;
#pragma unroll
                for (int r = 0; r < 4; ++r) vv[r] = f2bf(acc[fm][fn][r] + bv_[fn]);
                const int b = mbase >> 11, s = mbase & 2047, h = n >> 6, d = n & 63;
                u16* dst = outp + ((size_t)((b * 16 + h) * 64 + d)) * 2048 + s;
                *(u16x4*)dst = vv;
            } else {
                const float sc = (z == 0) ? QSCALE : 1.0f;
#pragma unroll
                for (int r = 0; r < 4; ++r) {
                    const float val = (acc[fm][fn][r] + bv_[fn]) * sc;
                    const int m = mbase + r;
                    const int b = m >> 11, s = m & 2047, h = n >> 6, d = n & 63;
                    outp[((size_t)((b * 16 + h) * 2048 + s)) * 64 + d] = f2bf(val);
                }
            }
        }
    }
}

// ---------------------------------------------------------------------------
// Output GEMM, 128x128 tile: fp32 out[m][n] = sum_k A[m][k]*W[n][k] + bias[n]
// ---------------------------------------------------------------------------
__global__ __launch_bounds__(256) void gemm_out(const u16* __restrict__ A,
                                                const u16* __restrict__ W,
                                                const float* __restrict__ bias,
                                                float* __restrict__ outp) {
    const int n0 = blockIdx.x * 128;
    const int m0 = blockIdx.y * 128;
    const int tid = threadIdx.x;
    const int lane = tid & 63, g = lane >> 4, c = lane & 15;
    const int w = tid >> 6, wm = w >> 1, wn = w & 1;

    __shared__ u16 lA[2][8192];
    __shared__ u16 lB[2][8192];

    auto stage = [&](int buf, int kt) {
#pragma unroll
        for (int i = 0; i < 4; ++i) {
            const int chunk = (w * 4 + i) * 64 + lane;
            const int r = chunk >> 3, sg = chunk & 7, ss = sg ^ (r & 7);
            glds16(A + (size_t)(m0 + r) * 1024 + kt * 64 + ss * 8, &lA[buf][(w * 4 + i) * 512]);
            glds16(W + (size_t)(n0 + r) * 1024 + kt * 64 + ss * 8, &lB[buf][(w * 4 + i) * 512]);
        }
    };

    f32x4 acc[4][4] = {};
    stage(0, 0);
    VMCNT0;
    __syncthreads();

    for (int kt = 0; kt < 16; ++kt) {
        const int buf = kt & 1;
        if (kt < 15) stage(buf ^ 1, kt + 1);
#pragma unroll
        for (int ks = 0; ks < 2; ++ks) {
            bf16x8 af[4], bfr[4];
#pragma unroll
            for (int fm = 0; fm < 4; ++fm) af[fm] = lds_read8(lA[buf], wm * 64 + fm * 16 + c, g * 8 + ks * 32);
#pragma unroll
            for (int fn = 0; fn < 4; ++fn) bfr[fn] = lds_read8(lB[buf], wn * 64 + fn * 16 + c, g * 8 + ks * 32);
#pragma unroll
            for (int fm = 0; fm < 4; ++fm)
#pragma unroll
                for (int fn = 0; fn < 4; ++fn)
                    acc[fm][fn] = mfma16x16(af[fm], bfr[fn], acc[fm][fn]);
        }
        VMCNT0;
        RAW_BAR();
    }

    float bv_[4];
#pragma unroll
    for (int fn = 0; fn < 4; ++fn) bv_[fn] = bias[n0 + wn * 64 + fn * 16 + c];

#pragma unroll
    for (int fm = 0; fm < 4; ++fm)
#pragma unroll
        for (int fn = 0; fn < 4; ++fn) {
            const int mbase = m0 + wm * 64 + fm * 16 + g * 4;
            const int n = n0 + wn * 64 + fn * 16 + c;
#pragma unroll
            for (int r = 0; r < 4; ++r)
                outp[(size_t)(mbase + r) * 1024 + n] = acc[fm][fn][r] + bv_[fn];
        }
}

// ---------------------------------------------------------------------------
// Attention (R4 configuration, verified 234 us): block = (bh, 128 q-rows),
// XCD-swizzled. 4 waves x 32 q-rows.
// Pass A: KVBLK=128 staging (16 barriers), S^T = mfma(K,Q), l = sum 2^s.
// Pass B: KVBLK=64, recompute S^T, P = 2^s * linv -> bf16 per-wave LDS,
//         PV MFMA, coalesced nontemporal fp32 attnW stores from LDS,
//         raw barrier + counted vmcnt(8) so stores stay in flight.
// LDS: lQ 16K + lKV union 32K + lP 16K = 64 KB -> 2 blocks/CU.
// ---------------------------------------------------------------------------
__global__ __launch_bounds__(256) void attn_kernel(const u16* __restrict__ Qh,
                                                   const u16* __restrict__ Kh,
                                                   const u16* __restrict__ Vt,
                                                   float* __restrict__ attnW,
                                                   u16* __restrict__ Obf) {
    const int bid = blockIdx.x;
    const int sw = ((bid & 7) << 6) + (bid >> 3);  // bijective: 512 % 8 == 0
    const int bh = sw >> 4, qt = sw & 15;
    const int tid = threadIdx.x;
    const int lane = tid & 63, g = lane >> 4, c = lane & 15;
    const int w = tid >> 6;

    __shared__ u16 lQ[8192];        // 128 x 64
    __shared__ u16 lKV[2][8192];    // pass A: K 128 rows; pass B: K64 | V64
    __shared__ u16 lP[4][2048];     // per-wave 32 x 64

    const u16* Qbase = Qh + ((size_t)bh * S_ + qt * 128) * D_;
    const u16* Kbase = Kh + (size_t)bh * S_ * D_;
    const u16* Vbase = Vt + (size_t)bh * D_ * S_;

#pragma unroll
    for (int i = 0; i < 4; ++i) {
        const int chunk = (w * 4 + i) * 64 + lane;
        const int r = chunk >> 3, sg = chunk & 7, ss = sg ^ (r & 7);
        glds16(Qbase + r * 64 + ss * 8, &lQ[(w * 4 + i) * 512]);
    }
    // pass A staging: 128 K rows per chunk
    auto stageK128 = [&](int buf, int kt2) {
#pragma unroll
        for (int i = 0; i < 4; ++i) {
            const int chunk = (w * 4 + i) * 64 + lane;
            const int r = chunk >> 3, sg = chunk & 7, ss = sg ^ (r & 7);
            glds16(Kbase + (size_t)(kt2 * 128 + r) * 64 + ss * 8, &lKV[buf][(w * 4 + i) * 512]);
        }
    };
    // pass B staging: 64 K rows -> lKV[buf][0..4095], 64 V rows -> [4096..8191]
    auto stageKV64 = [&](int buf, int kt) {
#pragma unroll
        for (int i = 0; i < 2; ++i) {
            const int chunk = (w * 2 + i) * 64 + lane;
            const int r = chunk >> 3, sg = chunk & 7, ss = sg ^ (r & 7);
            glds16(Kbase + (size_t)(kt * 64 + r) * 64 + ss * 8, &lKV[buf][(w * 2 + i) * 512]);
            glds16(Vbase + (size_t)r * S_ + kt * 64 + ss * 8, &lKV[buf][4096 + (w * 2 + i) * 512]);
        }
    };

    stageK128(0, 0);
    VMCNT0;
    __syncthreads();

    float l_run[2] = {0.f, 0.f};

    // ---- pass A: 16 iterations of 128 kv ----
    for (int kt2 = 0; kt2 < 16; ++kt2) {
        const int buf = kt2 & 1;
        if (kt2 < 15) stageK128(buf ^ 1, kt2 + 1);

#pragma unroll
        for (int sub = 0; sub < 2; ++sub) {
            f32x4 s[4][2] = {};
            __builtin_amdgcn_s_setprio(1);
#pragma unroll
            for (int ks = 0; ks < 2; ++ks) {
                bf16x8 a[4], b[2];
#pragma unroll
                for (int kf = 0; kf < 4; ++kf)
                    a[kf] = lds_read8(lKV[buf], sub * 64 + kf * 16 + c, g * 8 + ks * 32);
#pragma unroll
                for (int qf = 0; qf < 2; ++qf)
                    b[qf] = lds_read8(lQ, w * 32 + qf * 16 + c, g * 8 + ks * 32);
#pragma unroll
                for (int kf = 0; kf < 4; ++kf)
#pragma unroll
                    for (int qf = 0; qf < 2; ++qf)
                        s[kf][qf] = mfma16x16(a[kf], b[qf], s[kf][qf]);
            }
            __builtin_amdgcn_s_setprio(0);
#pragma unroll
            for (int qf = 0; qf < 2; ++qf) {
                float ts = 0.f;
#pragma unroll
                for (int kf = 0; kf < 4; ++kf)
#pragma unroll
                    for (int r = 0; r < 4; ++r) ts += exp2f(s[kf][qf][r]);
                ts += __shfl_xor(ts, 16);
                ts += __shfl_xor(ts, 32);
                l_run[qf] += ts;
            }
        }
        VMCNT0;
        RAW_BAR();
    }
    const float linv[2] = {1.f / l_run[0], 1.f / l_run[1]};

    f32x4 o[2][4] = {};
    stageKV64(0, 0);
    VMCNT0;
    RAW_BAR();

    // ---- pass B: 32 iterations of 64 kv ----
    for (int kt = 0; kt < 32; ++kt) {
        const int buf = kt & 1;
        if (kt < 31) stageKV64(buf ^ 1, kt + 1);

        f32x4 s[4][2] = {};
        __builtin_amdgcn_s_setprio(1);
#pragma unroll
        for (int ks = 0; ks < 2; ++ks) {
            bf16x8 a[4], b[2];
#pragma unroll
            for (int kf = 0; kf < 4; ++kf)
                a[kf] = lds_read8(lKV[buf], kf * 16 + c, g * 8 + ks * 32);
#pragma unroll
            for (int qf = 0; qf < 2; ++qf)
                b[qf] = lds_read8(lQ, w * 32 + qf * 16 + c, g * 8 + ks * 32);
#pragma unroll
            for (int kf = 0; kf < 4; ++kf)
#pragma unroll
                for (int qf = 0; qf < 2; ++qf)
                    s[kf][qf] = mfma16x16(a[kf], b[qf], s[kf][qf]);
        }
        __builtin_amdgcn_s_setprio(0);

        u16* myP = lP[w];
#pragma unroll
        for (int qf = 0; qf < 2; ++qf) {
#pragma unroll
            for (int kf = 0; kf < 4; ++kf) {
                f32x4 p4;
#pragma unroll
                for (int r = 0; r < 4; ++r) p4[r] = exp2f(s[kf][qf][r]) * linv[qf];
#pragma unroll
                for (int rp = 0; rp < 2; ++rp) {
                    const unsigned pk = (unsigned)f2bf(p4[2 * rp]) |
                                        ((unsigned)f2bf(p4[2 * rp + 1]) << 16);
                    const int row = qf * 16 + c;
                    const int col = kf * 16 + g * 4 + 2 * rp;
                    *(unsigned*)((char*)myP + (((row * 128) + (col * 2)) ^ ((row & 7) << 4))) = pk;
                }
            }
        }

        // PV: o[q][d] += P[q][kv] * V[kv][d]
        __builtin_amdgcn_s_setprio(1);
#pragma unroll
        for (int ks = 0; ks < 2; ++ks) {
            bf16x8 pa[2], vb[4];
#pragma unroll
            for (int fm = 0; fm < 2; ++fm) pa[fm] = lds_read8(myP, fm * 16 + c, g * 8 + ks * 32);
#pragma unroll
            for (int fn = 0; fn < 4; ++fn) vb[fn] = lds_read8(lKV[buf] + 4096, fn * 16 + c, g * 8 + ks * 32);
#pragma unroll
            for (int fm = 0; fm < 2; ++fm)
#pragma unroll
                for (int fn = 0; fn < 4; ++fn)
                    o[fm][fn] = mfma16x16(pa[fm], vb[fn], o[fm][fn]);
        }
        __builtin_amdgcn_s_setprio(0);

        // Coalesced NT attnW store from myP: 16 lanes x 16B = 256B per q-row.
        {
            const size_t qbase = (size_t)bh * S_ + (size_t)(qt * 128 + w * 32);
#pragma unroll
            for (int j = 0; j < 8; ++j) {
                const int row = j * 4 + g;  // 0..31 within this wave's q rows
                const unsigned long long pv8 = *(const unsigned long long*)(
                    (const char*)myP + (((row * 128) + c * 8) ^ ((row & 7) << 4)));
                f32x4 o4;
                o4[0] = bf2f((unsigned)(pv8 & 0xffffu));
                o4[1] = bf2f((unsigned)((pv8 >> 16) & 0xffffu));
                o4[2] = bf2f((unsigned)((pv8 >> 32) & 0xffffu));
                o4[3] = bf2f((unsigned)((pv8 >> 48) & 0xffffu));
                __builtin_nontemporal_store(
                    o4, (f32x4*)(attnW + (qbase + row) * S_ + kt * 64 + c * 4));
            }
        }

        // counted wait: this tile's 8 stores stay in flight; the oldest
        // outstanding (prev stores + this tile's 4 loads) must land.
        asm volatile("s_waitcnt vmcnt(8)" ::: "memory");
        RAW_BAR();
    }

    // write O as bf16 head-merged [b][s][h*64+d] (A-operand of final GEMM)
    const int b2 = bh >> 4, h = bh & 15;
#pragma unroll
    for (int fm = 0; fm < 2; ++fm)
#pragma unroll
        for (int fn = 0; fn < 4; ++fn)
#pragma unroll
            for (int r = 0; r < 4; ++r) {
                const int q = qt * 128 + w * 32 + fm * 16 + g * 4 + r;
                const int d = fn * 16 + c;
                __builtin_nontemporal_store(
                    f2bf(o[fm][fn][r]),
                    &Obf[((size_t)(b2 * S_ + q)) * E_ + h * 64 + d]);
            }
}

extern "C" void kernel_launch(void* const* d_in, const int* in_sizes, int n_in,
                              void* d_out, int out_size, void* d_ws, size_t ws_size,
                              hipStream_t stream) {
    const float* query = (const float*)d_in[0];
    const float* key_ = (const float*)d_in[1];
    const float* value = (const float*)d_in[2];
    const float* Wq = (const float*)d_in[3];
    const float* bq = (const float*)d_in[4];
    const float* Wk = (const float*)d_in[5];
    const float* bk = (const float*)d_in[6];
    const float* Wv = (const float*)d_in[7];
    const float* bv = (const float*)d_in[8];
    const float* Wo = (const float*)d_in[9];
    const float* bo = (const float*)d_in[10];

    // ws layout (u16 units):
    // [0,12M)   qbf,kbf,vbf   (aliased by Obf after projections consume them)
    // [12M,16M) Wq,Wk,Wv,Wo bf16
    // [16M,28M) Qh, Kh, Vt
    u16* qkv_bf = (u16*)d_ws;
    u16* w_bf = qkv_bf + (size_t)12 * 1024 * 1024;
    u16* Qh = qkv_bf + (size_t)16 * 1024 * 1024;
    u16* Obf = qkv_bf;  // alias: q/k/v bf16 dead once projections finish

    float* out0 = (float*)d_out;                 // [B,S,E]
    float* attnW = out0 + (size_t)B_ * S_ * E_;  // [B,H,S,S]

    cvt_kernel<<<8192, 256, 0, stream>>>(query, key_, value, Wq, Wk, Wv, Wo, qkv_bf, w_bf);

    gemm_qkv<<<dim3(8, 32, 3), 256, 0, stream>>>(qkv_bf, w_bf, bq, bk, bv, Qh);

    attn_kernel<<<512, 256, 0, stream>>>(Qh, Qh + (size_t)4 * 1024 * 1024,
                                         Qh + (size_t)8 * 1024 * 1024, attnW, Obf);

    gemm_out<<<dim3(8, 32), 256, 0, stream>>>(Obf, w_bf + (size_t)3 * 1024 * 1024, bo, (float*)d_out);
}